// Round 1
// baseline (432.535 us; speedup 1.0000x reference)
//
#include <hip/hip_runtime.h>

// Problem constants: x shape (16, 1, 2048, 2048) fp32.
#define B_  16
#define H_  2048
#define W_  2048
#define HO  (H_ / 2)       // 1024
#define WO  (W_ / 2)       // 1024
#define WQ  (W_ / 8)       // 256 quads of 8 input cols (= 4 output cols) per row
#define NBAND ((size_t)B_ * HO * WO)   // 16,777,216 elems per band

// _safe: replace non-finite with 0 (exponent-all-ones test, 2 VALU ops)
__device__ __forceinline__ float safef(float v) {
    unsigned u = __float_as_uint(v);
    return ((u & 0x7f800000u) == 0x7f800000u) ? 0.0f : v;
}

__device__ __forceinline__ float4 safef4(float4 v) {
    return make_float4(safef(v.x), safef(v.y), safef(v.z), safef(v.w));
}

// One thread: 2x8 input patch -> 4 output cols in each of 4 bands.
// Loads: 4x float4 (16B/lane, coalesced). Stores: 4x float4 (coalesced).
__global__ __launch_bounds__(256) void dwt2d_haar_kernel(
        const float* __restrict__ x, float* __restrict__ out) {
    unsigned t  = blockIdx.x * 256u + threadIdx.x;   // [0, 16*1024*256)
    unsigned wq = t & (WQ - 1);                      // quad index along W
    unsigned h2 = (t >> 8) & (HO - 1);               // output row
    unsigned b  = t >> 18;                           // batch

    size_t in_base = (size_t)b * H_ * W_ + (size_t)(2u * h2) * W_ + 8u * wq;
    const float4* top = reinterpret_cast<const float4*>(x + in_base);
    const float4* bot = reinterpret_cast<const float4*>(x + in_base + W_);

    float4 t0 = safef4(top[0]);
    float4 t1 = safef4(top[1]);
    float4 b0 = safef4(bot[0]);
    float4 b1 = safef4(bot[1]);

    float4 ll, lh, hl, hh;

    // k=0: a=t0.x b=t0.y c=b0.x d=b0.y
    ll.x = 0.5f * ( t0.x + t0.y + b0.x + b0.y);
    lh.x = 0.5f * (-t0.x + t0.y - b0.x + b0.y);
    hl.x = 0.5f * (-t0.x - t0.y + b0.x + b0.y);
    hh.x = 0.5f * ( t0.x - t0.y - b0.x + b0.y);
    // k=1
    ll.y = 0.5f * ( t0.z + t0.w + b0.z + b0.w);
    lh.y = 0.5f * (-t0.z + t0.w - b0.z + b0.w);
    hl.y = 0.5f * (-t0.z - t0.w + b0.z + b0.w);
    hh.y = 0.5f * ( t0.z - t0.w - b0.z + b0.w);
    // k=2
    ll.z = 0.5f * ( t1.x + t1.y + b1.x + b1.y);
    lh.z = 0.5f * (-t1.x + t1.y - b1.x + b1.y);
    hl.z = 0.5f * (-t1.x - t1.y + b1.x + b1.y);
    hh.z = 0.5f * ( t1.x - t1.y - b1.x + b1.y);
    // k=3
    ll.w = 0.5f * ( t1.z + t1.w + b1.z + b1.w);
    lh.w = 0.5f * (-t1.z + t1.w - b1.z + b1.w);
    hl.w = 0.5f * (-t1.z - t1.w + b1.z + b1.w);
    hh.w = 0.5f * ( t1.z - t1.w - b1.z + b1.w);

    size_t obase = (size_t)b * HO * WO + (size_t)h2 * WO + 4u * wq;
    *reinterpret_cast<float4*>(out + 0 * NBAND + obase) = ll;
    *reinterpret_cast<float4*>(out + 1 * NBAND + obase) = lh;
    *reinterpret_cast<float4*>(out + 2 * NBAND + obase) = hl;
    *reinterpret_cast<float4*>(out + 3 * NBAND + obase) = hh;
}

extern "C" void kernel_launch(void* const* d_in, const int* in_sizes, int n_in,
                              void* d_out, int out_size, void* d_ws, size_t ws_size,
                              hipStream_t stream) {
    const float* x = (const float*)d_in[0];
    float* out = (float*)d_out;
    // 16 * 1024 * 256 threads = 4,194,304 -> 16384 blocks of 256
    unsigned total_threads = B_ * HO * WQ;
    dim3 grid(total_threads / 256u);
    dim3 block(256);
    dwt2d_haar_kernel<<<grid, block, 0, stream>>>(x, out);
}